// Round 6
// baseline (566.679 us; speedup 1.0000x reference)
//
#include <hip/hip_runtime.h>
#include <math.h>

// ---------------------------------------------------------------------------
// TransFusion3: B=2, C1=512, H1=W1=96, C2=256, H2=W2=192, D=256, NH=8, hd=32,
// WQ=24x24, WK=12x12. 64 windows per image; q-window i aligns with k-window i.
// ---------------------------------------------------------------------------

#define HW1 9216L      // 96*96
#define HW2 36864L     // 192*192
#define M1  18432L     // 2*96*96
#define M2  73728L     // 2*192*192

typedef __attribute__((ext_vector_type(8))) short short8;
typedef __attribute__((ext_vector_type(4))) float f32x4;
typedef unsigned short u16;

__device__ __forceinline__ short f2bf(float f)
{
    unsigned u = __builtin_bit_cast(unsigned, f);
    u = (u + 0x7fff + ((u >> 16) & 1)) >> 16;   // RNE
    return (short)u;
}
__device__ __forceinline__ float bf2f(u16 u)
{
    unsigned x = ((unsigned)u) << 16;
    return __builtin_bit_cast(float, x);
}
__device__ __forceinline__ float gelu_exact(float v)
{
    return 0.5f * v * (1.0f + erff(v * 0.70710678118654752f));
}

// ---------------------------------------------------------------------------
// wcvt: one-time weight conversions.
// Transposed [N][K] jobs (16-k x 256-n tiles): proj 0..31, k 32..63, v 64..95,
// fc1 96..127 (16 kt x 2 n-halves), fc2 128..159.
// qwN (straight [ci][co] bf16 copy of q_w): 160..175.  kvb concat: 176.
// grid(177).
// ---------------------------------------------------------------------------
__global__ __launch_bounds__(256) void wcvt(
    const float* __restrict__ pw, const float* __restrict__ kw,
    const float* __restrict__ vw, const float* __restrict__ qw,
    const float* __restrict__ f1, const float* __restrict__ f2,
    const float* __restrict__ kb, const float* __restrict__ vb,
    u16* __restrict__ pwT, u16* __restrict__ kwT, u16* __restrict__ vwT,
    u16* __restrict__ f1T, u16* __restrict__ f2T,
    u16* __restrict__ qwN, float* __restrict__ kvb)
{
    int bx = blockIdx.x, t = threadIdx.x;
    if (bx >= 176) {                      // kvb concat
        kvb[t] = kb[t];
        kvb[256 + t] = vb[t];
        return;
    }
    if (bx >= 160) {                      // qwN straight bf16 copy
        int k0 = (bx - 160) * 16;
#pragma unroll
        for (int kk = 0; kk < 16; ++kk)
            qwN[(long)(k0 + kk) * 256 + t] = (u16)f2bf(qw[(long)(k0 + kk) * 256 + t]);
        return;
    }
    const float* src; u16* dst; int K, ldN = 256, kt, n0 = 0;
    if (bx < 32)       { src = pw; dst = pwT; K = 512; kt = bx; }
    else if (bx < 64)  { src = kw; dst = kwT; K = 512; kt = bx - 32; }
    else if (bx < 96)  { src = vw; dst = vwT; K = 512; kt = bx - 64; }
    else if (bx < 128) { int j = bx - 96; src = f1; dst = f1T; K = 256;
                         ldN = 512; kt = j >> 1; n0 = (j & 1) * 256; }
    else               { src = f2; dst = f2T; K = 512; kt = bx - 128; }
    int n = n0 + t, k0 = kt * 16;
    short s[16];
#pragma unroll
    for (int kk = 0; kk < 16; ++kk) s[kk] = f2bf(src[(long)(k0 + kk) * ldN + n]);
    *(short8*)&dst[(long)n * K + k0]     = *(short8*)&s[0];
    *(short8*)&dst[(long)n * K + k0 + 8] = *(short8*)&s[8];
}

// ---------------------------------------------------------------------------
__device__ __forceinline__ float pe4(int t, float e)
{
    if (t == 0) return sinf(e);
    if (t == 1) return cosf(e);
    if (t == 2) return sinf(e * 0.01f);
    return cosf(e * 0.01f);
}

// ---------------------------------------------------------------------------
// x1t: coalesced NCHW fp32 -> row-major bf16 transpose of x1 ([m][512]),
// with the pooled-k window sums AND the kg sine-pos folded in.
// grid 1536 = b*768 + cg*96 + y  (cg: 8 groups of 64 ch).
// ---------------------------------------------------------------------------
__global__ __launch_bounds__(256) void x1t(
    const float* __restrict__ x1, u16* __restrict__ x1bf, float* __restrict__ kg)
{
    __shared__ short T[6144];         // 96 pix x 32 words (64 ch bf16), swizzled
    __shared__ float rw[64][8];       // per-(ch, window-x) row partial sums
    const int blk = blockIdx.x;
    const int b = blk / 768, rem = blk % 768;
    const int cg = rem / 96, y = rem % 96;
    const int t = threadIdx.x;

    ((float2*)rw)[t] = float2{0.f, 0.f};
    __syncthreads();

    const float* src = x1 + ((long)(b * 512 + cg * 64)) * HW1 + (long)y * 96;
#pragma unroll
    for (int k = 0; k < 6; ++k) {
        int idx = t + k * 256;                 // < 1536
        int c = idx / 24, col4 = idx % 24;
        float4 v = *(const float4*)(src + (long)c * HW1 + col4 * 4);
        atomicAdd(&rw[c][col4 / 3], v.x + v.y + v.z + v.w);
        int chh = c >> 1, cb = c & 1;
        const float* vf = (const float*)&v;
#pragma unroll
        for (int j = 0; j < 4; ++j) {
            int pix = col4 * 4 + j;
            int word = pix * 32 + (chh ^ (((pix >> 2) & 7) << 2));
            T[word * 2 + cb] = f2bf(vf[j]);
        }
    }
    __syncthreads();
    u16* dst = x1bf + ((long)b * HW1 + (long)y * 96) * 512 + cg * 64;
#pragma unroll
    for (int k = 0; k < 3; ++k) {
        int idx = t + k * 256;                 // < 768
        int pix = idx >> 3, j = idx & 7;
        int w0 = pix * 32 + ((j * 4) ^ (((pix >> 2) & 7) << 2));
        *(short8*)(dst + (long)pix * 512 + j * 8) = *(short8*)&T[w0 * 2];
    }

    // pooled-k finalize: 512 cells (64 ch x 8 wx), 2 per thread
    {
        int wy = y / 12;
#pragma unroll
        for (int u = 0; u < 2; ++u) {
            int cell = t * 2 + u;
            int c = cell >> 3, wx = cell & 7;
            atomicAdd(kg + (long)(b * 64 + wy * 8 + wx) * 512 + cg * 64 + c,
                      rw[c][wx] * (1.0f / 144.0f));
        }
    }
    // kg sine-pos: added exactly once per (win, ch) by the y%12==0 blocks
    if (y % 12 == 0) {
        const float TWO_PI = 6.283185307179586f;
        int wy = y / 12;
#pragma unroll
        for (int u = 0; u < 2; ++u) {
            int cell = t * 2 + u;
            int gxx = cell & 7, c = cg * 64 + (cell >> 3);
            float pos;
            if (wy < 4) pos = pe4(wy,     (gxx + 1) * (TWO_PI / (8.0f + 1e-5f)));
            else        pos = pe4(wy - 4, (c + 1)   * (TWO_PI / (512.0f + 1e-5f)));
            atomicAdd(kg + (long)(b * 64 + wy * 8 + gxx) * 512 + c, pos);
        }
    }
}

// ---------------------------------------------------------------------------
// x2t: coalesced NCHW fp32 -> NHWC(pixel-major) bf16 transpose of x2, with the
// pooled-q window sums AND the qg sine-pos folded in. grid 1536.
// ---------------------------------------------------------------------------
__global__ __launch_bounds__(256) void x2t(
    const float* __restrict__ x2, u16* __restrict__ x2pm, float* __restrict__ qg)
{
    __shared__ short T[12288];        // 192 pix x 32 words (64 ch bf16), swizzled
    __shared__ float qsum[64][8];
    const int blk = blockIdx.x;
    const int b = blk / 768, rem = blk % 768;
    const int cg = rem / 192, h = rem % 192;
    const int t = threadIdx.x;

    ((float2*)qsum)[t] = float2{0.f, 0.f};
    __syncthreads();

    const float* src = x2 + ((long)(b * 256 + cg * 64) * 192 + h) * 192;
#pragma unroll
    for (int k = 0; k < 12; ++k) {
        int idx = t + k * 256;                 // < 3072
        int c = idx / 48, col4 = idx % 48;
        float4 v = *(const float4*)(src + (long)c * HW2 + col4 * 4);
        atomicAdd(&qsum[c][col4 / 6], v.x + v.y + v.z + v.w);
        int chh = c >> 1, cb = c & 1;
        const float* vf = (const float*)&v;
#pragma unroll
        for (int j = 0; j < 4; ++j) {
            int pix = col4 * 4 + j;
            int word = pix * 32 + (chh ^ (((pix >> 2) & 7) << 2));
            T[word * 2 + cb] = f2bf(vf[j]);
        }
    }
    __syncthreads();

    u16* dst = x2pm + ((long)b * HW2 + (long)h * 192) * 256 + cg * 64;
#pragma unroll
    for (int k = 0; k < 6; ++k) {
        int idx = t + k * 256;                 // < 1536
        int pix = idx >> 3, j = idx & 7;
        int w0 = pix * 32 + ((j * 4) ^ (((pix >> 2) & 7) << 2));
        *(short8*)(dst + (long)pix * 256 + j * 8) = *(short8*)&T[w0 * 2];
    }

    // pooled-q finalize: 512 cells, 2 per thread
    {
        int wy = h / 24;
#pragma unroll
        for (int u = 0; u < 2; ++u) {
            int cell = t * 2 + u;
            int c = cell >> 3, wx = cell & 7;
            atomicAdd(qg + (long)(b * 64 + wy * 8 + wx) * 256 + cg * 64 + c,
                      qsum[c][wx] * (1.0f / 576.0f));
        }
    }
    // qg sine-pos: added exactly once per (win, ch) by the h%24==0 blocks
    if (h % 24 == 0) {
        const float TWO_PI = 6.283185307179586f;
        int wy = h / 24;
#pragma unroll
        for (int u = 0; u < 2; ++u) {
            int cell = t * 2 + u;
            int gxx = cell & 7, c = cg * 64 + (cell >> 3);
            float pos;
            if (wy < 4) pos = pe4(wy,     (gxx + 1) * (TWO_PI / (8.0f + 1e-5f)));
            else        pos = pe4(wy - 4, (c + 1)   * (TWO_PI / (256.0f + 1e-5f)));
            atomicAdd(qg + (long)(b * 64 + wy * 8 + gxx) * 256 + c, pos);
        }
    }
}

// ---------------------------------------------------------------------------
// proj_ln: scb = LN(x1bf @ pwT^T + proj_b) -> bf16. BM=64, BN=256 (full row),
// K=512. LN in-register in the epilogue (16-lane-group shfl_xor reduce).
// grid(288).
// ---------------------------------------------------------------------------
__global__ __launch_bounds__(256) void proj_ln(
    const u16* __restrict__ A, const u16* __restrict__ BT,
    const float* __restrict__ bias, const float* __restrict__ g,
    const float* __restrict__ beta, u16* __restrict__ Cout)
{
    __shared__ short pool[64 * 72 + 256 * 72];   // As | Bs ; ob[64][264] aliases
    short* As = pool;
    short* Bs = pool + 64 * 72;
    const int t = threadIdx.x;
    const long m0 = (long)blockIdx.x * 64;
    const int w = t >> 6, lane = t & 63;
    const int lm = lane & 15, lq = lane >> 4;

    f32x4 acc[16] = {};
    for (int k0 = 0; k0 < 512; k0 += 64) {
#pragma unroll
        for (int it = 0; it < 2; ++it) {
            int idx = t + it * 256;
            int r = idx >> 3, q = idx & 7;
            *(short8*)&As[r * 72 + q * 8] = *(const short8*)(A + (m0 + r) * 512 + k0 + q * 8);
        }
#pragma unroll
        for (int it = 0; it < 8; ++it) {
            int idx = t + it * 256;
            int n = idx >> 3, q = idx & 7;
            *(short8*)&Bs[n * 72 + q * 8] = *(const short8*)(BT + (long)n * 512 + k0 + q * 8);
        }
        __syncthreads();
#pragma unroll
        for (int kk = 0; kk < 64; kk += 32) {
            short8 af = *(short8*)&As[(w * 16 + lm) * 72 + kk + lq * 8];
#pragma unroll
            for (int c = 0; c < 16; ++c) {
                short8 bf = *(short8*)&Bs[(c * 16 + lm) * 72 + kk + lq * 8];
                acc[c] = __builtin_amdgcn_mfma_f32_16x16x32_bf16(af, bf, acc[c], 0, 0, 0);
            }
        }
        __syncthreads();
    }
#pragma unroll
    for (int c = 0; c < 16; ++c) {
        float bv = bias[c * 16 + lm];
#pragma unroll
        for (int i = 0; i < 4; ++i) acc[c][i] += bv;
    }
    short* ob = pool;       // [64][264]
#pragma unroll
    for (int i = 0; i < 4; ++i) {
        float s = 0.f, s2 = 0.f;
#pragma unroll
        for (int c = 0; c < 16; ++c) { float v = acc[c][i]; s += v; s2 += v * v; }
#pragma unroll
        for (int o = 8; o > 0; o >>= 1) {
            s  += __shfl_xor(s,  o, 64);
            s2 += __shfl_xor(s2, o, 64);
        }
        float mean = s * (1.0f / 256.0f);
        float var  = s2 * (1.0f / 256.0f) - mean * mean;
        float rs   = rsqrtf(var + 1e-5f);
        int row = w * 16 + lq * 4 + i;
#pragma unroll
        for (int c = 0; c < 16; ++c) {
            int col = c * 16 + lm;
            ob[row * 264 + col] = f2bf((acc[c][i] - mean) * rs * g[col] + beta[col]);
        }
    }
    __syncthreads();
    {
        int sr = t >> 2, q4 = (t & 3) * 64;
        u16* Cp = Cout + (m0 + sr) * 256 + q4;
#pragma unroll
        for (int q = 0; q < 8; ++q)
            *(short8*)(Cp + q * 8) = *(short8*)&ob[sr * 264 + q4 + q * 8];
    }
}

// ---------------------------------------------------------------------------
// gemm_lds: C = A(bf16 [M][ldA]) @ BT^T + bias.  BT bf16 [N][K] (n-major).
// BM=BN=128, BK=64, mfma 16x16x32. bf16 out via LDS repack. EPI 1 = gelu.
// ---------------------------------------------------------------------------
template<int EPI>
__global__ __launch_bounds__(256) void gemm_lds(
    const u16* __restrict__ A, const u16* __restrict__ BT,
    const float* __restrict__ bias, u16* __restrict__ C,
    int N, int K, int ldA)
{
    __shared__ short pool[18432];  // As[128][72] Bs[128][72] | ob[128][136]
    short* As = pool;
    short* Bs = pool + 128 * 72;
    const int tid = threadIdx.x;
    const int m0 = blockIdx.y * 128;
    const int n0 = blockIdx.x * 128;
    const int w = tid >> 6, lane = tid & 63;
    const int wm = (w & 1) * 64, wn = (w >> 1) * 64;
    const int lm = lane & 15, lq = lane >> 4;

    const int sr = tid >> 1, sh = (tid & 1) * 32;
    const u16* Ap = A  + (long)(m0 + sr) * ldA + sh;
    const u16* Bp = BT + (long)(n0 + sr) * K   + sh;

    f32x4 acc[4][4] = {};

    for (int k0 = 0; k0 < K; k0 += 64) {
#pragma unroll
        for (int q = 0; q < 4; ++q)
            *(short8*)&As[sr * 72 + sh + q * 8] = *(const short8*)(Ap + k0 + q * 8);
#pragma unroll
        for (int q = 0; q < 4; ++q)
            *(short8*)&Bs[sr * 72 + sh + q * 8] = *(const short8*)(Bp + k0 + q * 8);
        __syncthreads();
#pragma unroll
        for (int kk = 0; kk < 64; kk += 32) {
            short8 af[4], bfr[4];
#pragma unroll
            for (int r = 0; r < 4; ++r) af[r]  = *(short8*)&As[(wm + r * 16 + lm) * 72 + kk + lq * 8];
#pragma unroll
            for (int c = 0; c < 4; ++c) bfr[c] = *(short8*)&Bs[(wn + c * 16 + lm) * 72 + kk + lq * 8];
#pragma unroll
            for (int r = 0; r < 4; ++r)
#pragma unroll
                for (int c = 0; c < 4; ++c)
                    acc[r][c] = __builtin_amdgcn_mfma_f32_16x16x32_bf16(af[r], bfr[c], acc[r][c], 0, 0, 0);
        }
        __syncthreads();
    }

    short* ob = pool;   // [128][136]
#pragma unroll
    for (int r = 0; r < 4; ++r)
#pragma unroll
        for (int i = 0; i < 4; ++i) {
            int row = wm + r * 16 + lq * 4 + i;
#pragma unroll
            for (int c = 0; c < 4; ++c) {
                int jl = wn + c * 16 + lm;
                float v = acc[r][c][i] + bias[n0 + jl];
                if (EPI == 1) v = gelu_exact(v);
                ob[row * 136 + jl] = f2bf(v);
            }
        }
    __syncthreads();
    int m = tid >> 1, half = (tid & 1) * 64;
    u16* Cp = C + (long)(m0 + m) * N + n0 + half;
#pragma unroll
    for (int q = 0; q < 8; ++q)
        *(short8*)(Cp + q * 8) = *(short8*)&ob[m * 136 + half + q * 8];
}

// ---------------------------------------------------------------------------
// ktv_w: per (window, head): KtV = K^T V (MFMA), then the folded attention
// matrix W'T[co=h*32+j][ci] = sum_t KtV[t][j] * q_w[ci][h*32+t]  (bf16) and
// bias' = bq_h @ KtV. 1-wave blocks (no barriers needed). grid(1024).
// ---------------------------------------------------------------------------
__global__ __launch_bounds__(64) void ktv_w(
    const u16* __restrict__ kv16, const u16* __restrict__ qwN,
    const float* __restrict__ qb, u16* __restrict__ wT, float* __restrict__ bias_w)
{
    __shared__ short pool[10368 + 1280]; // kt[32*162] vt[32*162] | wout[32*264]
    short* kt  = pool;
    short* vt  = pool + 5184;
    short* kt2 = pool + 10368;           // [32][40]: kt2[j][t] = KtV[t][j]
    short* wout = pool;                  // aliases kt+vt (dead after KtV)

    const int blk = blockIdx.x;     // win*8 + head
    const int win = blk >> 3, hd = blk & 7;
    const int b = win >> 6, wy = (win >> 3) & 7, wx = win & 7;
    const int t = threadIdx.x;
    const int lm = t & 15, lq = t >> 4;

    // zero the p = 144..159 pad
    {
        int c = t >> 1, p0 = 144 + (t & 1) * 8;
#pragma unroll
        for (int j = 0; j < 8; ++j) {
            kt[c * 162 + p0 + j] = 0;
            vt[c * 162 + p0 + j] = 0;
        }
    }
    // stage transposed K/V tiles from combined kv16 [m][512]
    const int pq = t >> 2, c8 = (t & 3) * 8;
#pragma unroll
    for (int it = 0; it < 9; ++it) {
        int p = it * 16 + pq;
        int py = p / 12, px = p % 12;
        long m = (long)b * HW1 + (long)(wy * 12 + py) * 96 + wx * 12 + px;
        short8 kvk = *(const short8*)(kv16 + m * 512 + hd * 32 + c8);
        short8 kvv = *(const short8*)(kv16 + m * 512 + 256 + hd * 32 + c8);
#pragma unroll
        for (int j = 0; j < 8; ++j) {
            kt[(c8 + j) * 162 + p] = kvk[j];
            vt[(c8 + j) * 162 + p] = kvv[j];
        }
    }
    __syncthreads();
    // KtV[i][j] = sum_p K[p][i] V[p][j]
    f32x4 acc[2][2] = {};
#pragma unroll
    for (int kk = 0; kk < 160; kk += 32) {
        short8 af[2], bf[2];
#pragma unroll
        for (int r = 0; r < 2; ++r) af[r] = *(short8*)&kt[(r * 16 + lm) * 162 + kk + lq * 8];
#pragma unroll
        for (int c = 0; c < 2; ++c) bf[c] = *(short8*)&vt[(c * 16 + lm) * 162 + kk + lq * 8];
#pragma unroll
        for (int r = 0; r < 2; ++r)
#pragma unroll
            for (int c = 0; c < 2; ++c)
                acc[r][c] = __builtin_amdgcn_mfma_f32_16x16x32_bf16(af[r], bf[c], acc[r][c], 0, 0, 0);
    }
    // kt2[j][t] = KtV[t][j]  (C layout: m=t=r*16+lq*4+i, n=j=c*16+lm)
#pragma unroll
    for (int r = 0; r < 2; ++r)
#pragma unroll
        for (int c = 0; c < 2; ++c)
#pragma unroll
            for (int i = 0; i < 4; ++i)
                kt2[(c * 16 + lm) * 40 + r * 16 + lq * 4 + i] = f2bf(acc[r][c][i]);
    __syncthreads();
    // bias' = bq_h @ KtV  (fp32)
    if (t < 32) {
        float s = 0.f;
#pragma unroll
        for (int tt = 0; tt < 32; ++tt)
            s += bf2f((u16)kt2[t * 40 + tt]) * qb[hd * 32 + tt];
        bias_w[(long)blk * 32 + t] = s;
    }
    // W'T[j][ci] = sum_t kt2[j][t] * qwN[ci][hd*32+t]
    short8 af2[2];
#pragma unroll
    for (int r = 0; r < 2; ++r) af2[r] = *(short8*)&kt2[(r * 16 + lm) * 40 + lq * 8];
#pragma unroll
    for (int nt = 0; nt < 16; ++nt) {
        short8 bf = *(const short8*)(qwN + (long)(nt * 16 + lm) * 256 + hd * 32 + lq * 8);
        f32x4 a2[2] = {};
#pragma unroll
        for (int r = 0; r < 2; ++r)
            a2[r] = __builtin_amdgcn_mfma_f32_16x16x32_bf16(af2[r], bf, a2[r], 0, 0, 0);
#pragma unroll
        for (int r = 0; r < 2; ++r)
#pragma unroll
            for (int i = 0; i < 4; ++i)
                wout[(r * 16 + lq * 4 + i) * 264 + nt * 16 + lm] = f2bf(a2[r][i]);
    }
    __syncthreads();
    {
        int row = t >> 1, half = (t & 1) * 128;
        u16* dst = wT + ((long)blk * 32 + row) * 256 + half;
#pragma unroll
        for (int q = 0; q < 16; ++q)
            *(short8*)(dst + q * 8) = *(short8*)&wout[row * 264 + half + q * 8];
    }
}

// ---------------------------------------------------------------------------
// wattn_ln3: fused  hln = LN( x2 + x2@W'_win + b'_win + up(og) ) -> bf16.
// W' = Wq @ blockdiag(KtV) precomputed by ktv_w. Block = one 2-row window
// strip (48 px) x 256 ch. grid(1536). One barrier total.
// ---------------------------------------------------------------------------
__global__ __launch_bounds__(256) void wattn_ln3(
    const u16* __restrict__ x2pm, const u16* __restrict__ wT,
    const float* __restrict__ bias_w, const float* __restrict__ og,
    u16* __restrict__ hln, const float* __restrict__ n1g,
    const float* __restrict__ n1b)
{
    __shared__ short qs[48 * 288];           // 27648 B

    const int t = threadIdx.x;
    const int blk = blockIdx.x;              // win*12 + strip
    const int strip = blk % 12, win = blk / 12;
    const int b = win >> 6, wy = (win >> 3) & 7, wxw = win & 7;
    const int hh0 = wy * 24 + strip * 2;
    const int w = t >> 6, lane = t & 63;
    const int lm = lane & 15, lq = lane >> 4;

    long pbase[3];
#pragma unroll
    for (int r = 0; r < 3; ++r) {
        int p = r * 16 + lm;
        pbase[r] = ((long)b * HW2 + (long)(hh0 + p / 24) * 192 + wxw * 24 + (p % 24)) * 256;
    }
    const u16* wbase = wT + (long)win * 256 * 256;   // rows indexed by co

    // ---- phase 1: o = x2 @ W'^T (+ b') ----
    f32x4 acc[3][4] = {};
#pragma unroll 2
    for (int kc = 0; kc < 8; ++kc) {
        const int ko = kc * 32 + lq * 8;
        short8 af[3], bfr[4];
#pragma unroll
        for (int r = 0; r < 3; ++r)
            af[r] = *(const short8*)(x2pm + pbase[r] + ko);
#pragma unroll
        for (int c = 0; c < 4; ++c)
            bfr[c] = *(const short8*)(wbase + (long)(w * 64 + c * 16 + lm) * 256 + ko);
#pragma unroll
        for (int r = 0; r < 3; ++r)
#pragma unroll
            for (int c = 0; c < 4; ++c)
                acc[r][c] = __builtin_amdgcn_mfma_f32_16x16x32_bf16(af[r], bfr[c], acc[r][c], 0, 0, 0);
    }

    // ---- o (+b') -> qs bf16 (XOR-swizzled <<4: conflict-free writes) ----
#pragma unroll
    for (int c = 0; c < 4; ++c) {
        float bv = bias_w[(long)win * 256 + w * 64 + c * 16 + lm];
#pragma unroll
        for (int r = 0; r < 3; ++r)
#pragma unroll
            for (int i = 0; i < 4; ++i) {
                int p = r * 16 + lq * 4 + i;
                int col = w * 64 + c * 16 + lm;
                qs[p * 288 + (col ^ (((p >> 2) & 3) << 4))] = f2bf(acc[r][c][i] + bv);
            }
    }
    __syncthreads();

    // ---- phase 3: x = resid + o + up(og); LN over 256 ch; wave w: 12 px ----
    float4 g4 = *(const float4*)(n1g + lane * 4);
    float4 b4 = *(const float4*)(n1b + lane * 4);
    const float* ogb0 = og + (long)b * 64 * 256;
#pragma unroll
    for (int pp = 0; pp < 12; ++pp) {
        int p = w * 12 + pp;
        int hh = hh0 + (p / 24), ww = wxw * 24 + (p % 24);
        float fy = hh * (7.0f / 191.0f);
        int y0 = (int)fy; int y1 = min(y0 + 1, 7); float wyf = fy - y0;
        float fx = ww * (7.0f / 191.0f);
        int x0 = (int)fx; int x1 = min(x0 + 1, 7); float wxf = fx - x0;
        float w00 = (1.f - wyf) * (1.f - wxf), w01 = (1.f - wyf) * wxf;
        float w10 = wyf * (1.f - wxf),         w11 = wyf * wxf;
        float4 q00 = *(const float4*)(ogb0 + (y0 * 8 + x0) * 256 + lane * 4);
        float4 q01 = *(const float4*)(ogb0 + (y0 * 8 + x1) * 256 + lane * 4);
        float4 q10 = *(const float4*)(ogb0 + (y1 * 8 + x0) * 256 + lane * 4);
        float4 q11 = *(const float4*)(ogb0 + (y1 * 8 + x1) * 256 + lane * 4);
        long pix = (long)b * HW2 + (long)hh * 192 + ww;
        ushort4 rv = *(const ushort4*)(x2pm + pix * 256 + lane * 4);
        int sw = ((p >> 2) & 3) << 4;
        ushort4 ov = *(ushort4*)&qs[p * 288 + ((lane * 4) ^ sw)];
        float xv0 = bf2f(rv.x) + bf2f(ov.x) + (w00 * q00.x + w01 * q01.x + w10 * q10.x + w11 * q11.x);
        float xv1 = bf2f(rv.y) + bf2f(ov.y) + (w00 * q00.y + w01 * q01.y + w10 * q10.y + w11 * q11.y);
        float xv2 = bf2f(rv.z) + bf2f(ov.z) + (w00 * q00.z + w01 * q01.z + w10 * q10.z + w11 * q11.z);
        float xv3 = bf2f(rv.w) + bf2f(ov.w) + (w00 * q00.w + w01 * q01.w + w10 * q10.w + w11 * q11.w);
        float s  = xv0 + xv1 + xv2 + xv3;
        float s2 = xv0 * xv0 + xv1 * xv1 + xv2 * xv2 + xv3 * xv3;
#pragma unroll
        for (int o = 32; o > 0; o >>= 1) {
            s  += __shfl_xor(s,  o, 64);
            s2 += __shfl_xor(s2, o, 64);
        }
        float mean = s * (1.0f / 256.0f);
        float var  = s2 * (1.0f / 256.0f) - mean * mean;
        float rs   = rsqrtf(var + 1e-5f);
        ushort4 o4;
        o4.x = (u16)f2bf((xv0 - mean) * rs * g4.x + b4.x);
        o4.y = (u16)f2bf((xv1 - mean) * rs * g4.y + b4.y);
        o4.z = (u16)f2bf((xv2 - mean) * rs * g4.z + b4.z);
        o4.w = (u16)f2bf((xv3 - mean) * rs * g4.w + b4.w);
        *(ushort4*)(hln + pix * 256 + lane * 4) = o4;
    }
}

// ---------------------------------------------------------------------------
// gemm64m: the three global-branch 128x256 projections in ONE launch.
// grid(4,2,3): z=0 qg@q2_w->qg2, z=1 kg@k2_w->kg2, z=2 kg@v2_w->vgb.
// ---------------------------------------------------------------------------
__global__ __launch_bounds__(256) void gemm64m(
    const float* __restrict__ qg, const float* __restrict__ kg,
    const float* __restrict__ q2w, const float* __restrict__ q2b,
    const float* __restrict__ k2w, const float* __restrict__ k2b,
    const float* __restrict__ v2w, const float* __restrict__ v2b,
    float* __restrict__ qg2, float* __restrict__ kg2, float* __restrict__ vgb)
{
    const float* A; const float* Bm; const float* bias; float* C; int K, ldA;
    int z = blockIdx.z;
    if (z == 0)      { A = qg; Bm = q2w; bias = q2b; C = qg2; K = 256; ldA = 256; }
    else if (z == 1) { A = kg; Bm = k2w; bias = k2b; C = kg2; K = 512; ldA = 512; }
    else             { A = kg; Bm = v2w; bias = v2b; C = vgb; K = 512; ldA = 512; }
    const int N = 256;
    constexpr int BK = 16;
    __shared__ float As[BK][68];
    __shared__ float Bs[BK][68];
    const int tid = threadIdx.x;
    const int m0 = blockIdx.y * 64;
    const int n0 = blockIdx.x * 64;
    const int tm = (tid >> 4) << 2;
    const int tn = (tid & 15) << 2;
    float acc[4][4] = {};
    for (int k0 = 0; k0 < K; k0 += BK) {
#pragma unroll
        for (int it = 0; it < 4; ++it) {
            int idx = tid + it * 256;
            int my = idx >> 4, kx = idx & 15;
            As[kx][my] = A[(long)(m0 + my) * ldA + (k0 + kx)];
        }
#pragma unroll
        for (int it = 0; it < 4; ++it) {
            int idx = tid + it * 256;
            int ky = idx >> 6, nx = idx & 63;
            Bs[ky][nx] = Bm[(long)(k0 + ky) * N + (n0 + nx)];
        }
        __syncthreads();
#pragma unroll
        for (int kk = 0; kk < BK; ++kk) {
            float a[4], b[4];
#pragma unroll
            for (int i = 0; i < 4; ++i) a[i] = As[kk][tm + i];
#pragma unroll
            for (int j = 0; j < 4; ++j) b[j] = Bs[kk][tn + j];
#pragma unroll
            for (int i = 0; i < 4; ++i)
#pragma unroll
                for (int j = 0; j < 4; ++j) acc[i][j] += a[i] * b[j];
        }
        __syncthreads();
    }
#pragma unroll
    for (int i = 0; i < 4; ++i) {
        long row = (long)(m0 + tm + i) * N;
#pragma unroll
        for (int j = 0; j < 4; ++j)
            C[row + n0 + tn + j] = acc[i][j] + bias[n0 + tn + j];
    }
}

// ---------------------------------------------------------------------------
__global__ __launch_bounds__(256) void gattn(
    const float* __restrict__ qg2, const float* __restrict__ kg2,
    const float* __restrict__ vg, float* __restrict__ og)
{
    __shared__ float qh[64][33], kh[64][33], vh[64][33];
    __shared__ float S[64][65];
    __shared__ float rinv[64];
    int blk = blockIdx.x;
    int b = blk >> 3, hd = blk & 7;
    int t = threadIdx.x;
#pragma unroll
    for (int it = 0; it < 8; ++it) {
        int idx = t + it * 256;
        int n = idx >> 5, i = idx & 31;
        long src = (long)(b * 64 + n) * 256 + hd * 32 + i;
        qh[n][i] = qg2[src];
        kh[n][i] = kg2[src];
        vh[n][i] = vg[src];
    }
    __syncthreads();
    int r = t >> 2, qq = t & 3, c0 = qq * 16;
    for (int c = c0; c < c0 + 16; ++c) {
        float s = 0.f;
#pragma unroll
        for (int i = 0; i < 32; ++i) s += qh[r][i] * kh[c][i];
        S[r][c] = s;
    }
    __syncthreads();
    float mx = -1e30f;
    for (int c = c0; c < c0 + 16; ++c) mx = fmaxf(mx, S[r][c]);
    mx = fmaxf(mx, __shfl_xor(mx, 1, 64));
    mx = fmaxf(mx, __shfl_xor(mx, 2, 64));
    float sm = 0.f;
    for (int c = c0; c < c0 + 16; ++c) {
        float e = expf(S[r][c] - mx);
        S[r][c] = e;
        sm += e;
    }
    sm += __shfl_xor(sm, 1, 64);
    sm += __shfl_xor(sm, 2, 64);
    if (qq == 0) rinv[r] = 1.0f / sm;
    __syncthreads();
    int n = t >> 2, j0 = (t & 3) * 8;
    float inv = rinv[n];
    for (int j = j0; j < j0 + 8; ++j) {
        float s = 0.f;
        for (int c = 0; c < 64; ++c) s += S[n][c] * vh[c][j];
        og[(long)(b * 64 + n) * 256 + hd * 32 + j] = s * inv;
    }
}

// ---------------------------------------------------------------------------
// out = LN(mlp + bilinear_ac(sc, 96->192)) -> NCHW fp32. bf16 inputs.
// ---------------------------------------------------------------------------
__global__ __launch_bounds__(256) void final_k3(
    const u16* __restrict__ mlp, const u16* __restrict__ sc,
    const float* __restrict__ g, const float* __restrict__ bb,
    float* __restrict__ out)
{
    __shared__ float lnb[32][258];
    int blk = blockIdx.x;              // b*1152 + hh*6 + strip
    int b = blk / 1152;
    int rem = blk - b * 1152;
    int hh = rem / 6, ww0 = (rem % 6) * 32;
    int wv = threadIdx.x >> 6, lane = threadIdx.x & 63;
    int c0 = lane * 4;
    float4 g4 = *(const float4*)(g + c0);
    float4 b4 = *(const float4*)(bb + c0);
    float fy = hh * (95.0f / 191.0f);
    int y0 = (int)fy; int y1 = min(y0 + 1, 95); float wy = fy - y0;
    const u16* scb = sc + (long)b * 9216 * 256 + c0;
#pragma unroll
    for (int i = 0; i < 8; ++i) {
        int p = wv * 8 + i;
        int ww = ww0 + p;
        float fx = ww * (95.0f / 191.0f);
        int x0 = (int)fx; int x1 = min(x0 + 1, 95); float wx = fx - x0;
        ushort4 u00 = *(const ushort4*)(scb + (long)(y0 * 96 + x0) * 256);
        ushort4 u01 = *(const ushort4*)(scb + (long)(y0 * 96 + x1) * 256);
        ushort4 u10 = *(const ushort4*)(scb + (long)(y1 * 96 + x0) * 256);
        ushort4 u11 = *(const ushort4*)(scb + (long)(y1 * 96 + x1) * 256);
        long m = ((long)b * 192 + hh) * 192 + ww;
        ushort4 um = *(const ushort4*)(mlp + m * 256 + c0);
        float w00 = (1.f - wy) * (1.f - wx), w01 = (1.f - wy) * wx;
        float w10 = wy * (1.f - wx),         w11 = wy * wx;
        float xv0 = bf2f(um.x) + w00 * bf2f(u00.x) + w01 * bf2f(u01.x) + w10 * bf2f(u10.x) + w11 * bf2f(u11.x);
        float xv1 = bf2f(um.y) + w00 * bf2f(u00.y) + w01 * bf2f(u01.y) + w10 * bf2f(u10.y) + w11 * bf2f(u11.y);
        float xv2 = bf2f(um.z) + w00 * bf2f(u00.z) + w01 * bf2f(u01.z) + w10 * bf2f(u10.z) + w11 * bf2f(u11.z);
        float xv3 = bf2f(um.w) + w00 * bf2f(u00.w) + w01 * bf2f(u01.w) + w10 * bf2f(u10.w) + w11 * bf2f(u11.w);
        float s  = xv0 + xv1 + xv2 + xv3;
        float s2 = xv0 * xv0 + xv1 * xv1 + xv2 * xv2 + xv3 * xv3;
#pragma unroll
        for (int o = 32; o > 0; o >>= 1) {
            s  += __shfl_xor(s,  o, 64);
            s2 += __shfl_xor(s2, o, 64);
        }
        float mean = s * (1.0f / 256.0f);
        float var  = s2 * (1.0f / 256.0f) - mean * mean;
        float rs   = rsqrtf(var + 1e-5f);
        lnb[p][c0 + 0] = (xv0 - mean) * rs * g4.x + b4.x;
        lnb[p][c0 + 1] = (xv1 - mean) * rs * g4.y + b4.y;
        lnb[p][c0 + 2] = (xv2 - mean) * rs * g4.z + b4.z;
        lnb[p][c0 + 3] = (xv3 - mean) * rs * g4.w + b4.w;
    }
    __syncthreads();
    int tw = threadIdx.x & 31, cg = threadIdx.x >> 5;
#pragma unroll
    for (int cc = 0; cc < 32; ++cc) {
        int c = cg * 32 + cc;
        out[((long)(b * 256 + c) * 192 + hh) * 192 + ww0 + tw] = lnb[tw][c];
    }
}

// ---------------------------------------------------------------------------
extern "C" void kernel_launch(void* const* d_in, const int* in_sizes, int n_in,
                              void* d_out, int out_size, void* d_ws, size_t ws_size,
                              hipStream_t stream)
{
    const float* x1     = (const float*)d_in[0];
    const float* x2     = (const float*)d_in[1];
    const float* q_w    = (const float*)d_in[2];
    const float* q_b    = (const float*)d_in[3];
    const float* k_w    = (const float*)d_in[4];
    const float* k_b    = (const float*)d_in[5];
    const float* v_w    = (const float*)d_in[6];
    const float* v_b    = (const float*)d_in[7];
    const float* q2_w   = (const float*)d_in[8];
    const float* q2_b   = (const float*)d_in[9];
    const float* k2_w   = (const float*)d_in[10];
    const float* k2_b   = (const float*)d_in[11];
    const float* v2_w   = (const float*)d_in[12];
    const float* v2_b   = (const float*)d_in[13];
    const float* proj_w = (const float*)d_in[14];
    const float* proj_b = (const float*)d_in[15];
    const float* proj_g = (const float*)d_in[16];
    const float* proj_bt= (const float*)d_in[17];
    const float* n1_g   = (const float*)d_in[18];
    const float* n1_b   = (const float*)d_in[19];
    const float* n2_g   = (const float*)d_in[20];
    const float* n2_b   = (const float*)d_in[21];
    const float* fc1_w  = (const float*)d_in[22];
    const float* fc1_b  = (const float*)d_in[23];
    const float* fc2_w  = (const float*)d_in[24];
    const float* fc2_b  = (const float*)d_in[25];
    float* out = (float*)d_out;

    // workspace carve (bytes)
    char* p = (char*)d_ws;
    u16*   scb  = (u16*)p;    p += M1 * 256 * 2;        //  9.4 MB sc bf16
    u16*   pwT  = (u16*)p;    p += 262144;              //  weight slabs bf16 [N][K]
    u16*   kwT  = (u16*)p;    p += 262144;              //  (kwT+vwT contiguous = kv)
    u16*   vwT  = (u16*)p;    p += 262144;
    u16*   f1T  = (u16*)p;    p += 262144;
    u16*   f2T  = (u16*)p;    p += 262144;
    u16*   qwN  = (u16*)p;    p += 131072;              //  q_w bf16 [ci][co]
    float* kvb  = (float*)p;  p += 2048;                //  concat k_b|v_b
    float* bias_w = (float*)p; p += 131072;             //  b' per (win,co)
    u16*   wT   = (u16*)p;    p += 1024L * 32 * 256 * 2;//  16.8 MB W'T
    u16*   kv16 = (u16*)p;    p += M1 * 512 * 2;        //  18.9 MB k|v bf16
    u16*   hln  = (u16*)p;    p += M2 * 256 * 2;        //  37.7 MB
    u16*   h1c  = (u16*)p;    p += 36864L * 512 * 2;    //  37.7 MB (half-M hidden)
    u16*   mlpb = (u16*)p;    p += M2 * 256 * 2;        //  37.7 MB
    float* qg   = (float*)p;  p += 128L * 256 * 4;
    float* kg   = (float*)p;  p += 128L * 512 * 4;
    float* qg2  = (float*)p;  p += 128L * 256 * 4;
    float* kg2  = (float*)p;  p += 128L * 256 * 4;
    float* vgb  = (float*)p;  p += 128L * 256 * 4;
    float* ogb  = (float*)p;  p += 128L * 256 * 4;

    // aliases with disjoint lifetimes:
    u16* x2pm = mlpb;   // [x2t .. wattn_ln3] vs [MLP .. final_k3]
    u16* x1bf = hln;    // [x1t .. kv gemm]   vs [wattn_ln3 .. MLP]

    dim3 blk(256);

    // 0) zero pooled accumulators (qg & kg contiguous)
    hipMemsetAsync(qg, 0, (128L * 256 + 128L * 512) * 4, stream);

    // 1) one-time conversions; x1/x2 transposes with pooled sums + pos folded
    wcvt<<<dim3(177), blk, 0, stream>>>(proj_w, k_w, v_w, q_w, fc1_w, fc2_w,
                                        k_b, v_b, pwT, kwT, vwT, f1T, f2T,
                                        qwN, kvb);
    x1t<<<dim3(1536), blk, 0, stream>>>(x1, x1bf, kg);
    x2t<<<dim3(1536), blk, 0, stream>>>(x2, x2pm, qg);

    // 2) proj GEMM with fused LN -> bf16 sc
    proj_ln<<<dim3(288), blk, 0, stream>>>(x1bf, pwT, proj_b, proj_g, proj_bt, scb);

    // 3) k & v projections in ONE launch (N=512, kwT|vwT contiguous)
    gemm_lds<0><<<dim3(4, 144), blk, 0, stream>>>(x1bf, kwT, kvb, kv16, 512, 512, 512);

    // 4) per (window, head): KtV then folded W' and b'
    ktv_w<<<dim3(1024), dim3(64), 0, stream>>>(kv16, qwN, q_b, wT, bias_w);

    // 5-6) global projections (one launch) + global softmax attention
    gemm64m<<<dim3(4, 2, 3), blk, 0, stream>>>(qg, kg, q2_w, q2_b, k2_w, k2_b,
                                               v2_w, v2_b, qg2, kg2, vgb);
    gattn<<<dim3(16), blk, 0, stream>>>(qg2, kg2, vgb, ogb);

    // 7) fused folded-attn + residual + og upsample + LN1
    wattn_ln3<<<dim3(1536), blk, 0, stream>>>(x2pm, wT, bias_w, ogb, hln, n1_g, n1_b);

    // 8-9) MLP via LDS-staged GEMMs, 2 chunks x 2 launches (36864 rows each)
    for (int c2 = 0; c2 < 2; ++c2) {
        const u16* aoff = hln  + (long)c2 * 36864 * 256;
        u16*       coff = mlpb + (long)c2 * 36864 * 256;
        gemm_lds<1><<<dim3(4, 288), blk, 0, stream>>>(aoff, f1T, fc1_b, h1c, 512, 256, 256);
        gemm_lds<0><<<dim3(2, 288), blk, 0, stream>>>(h1c, f2T, fc2_b, coff, 256, 512, 512);
    }

    // 10) out = LN(mlp + upsample(sc)) -> NCHW
    final_k3<<<dim3(2304), blk, 0, stream>>>(mlpb, scb, n2_g, n2_b, out);
}

// Round 7
// 561.658 us; speedup vs baseline: 1.0089x; 1.0089x over previous
//
#include <hip/hip_runtime.h>
#include <math.h>

// ---------------------------------------------------------------------------
// TransFusion3: B=2, C1=512, H1=W1=96, C2=256, H2=W2=192, D=256, NH=8, hd=32,
// WQ=24x24, WK=12x12. 64 windows per image; q-window i aligns with k-window i.
// ---------------------------------------------------------------------------

#define HW1 9216L      // 96*96
#define HW2 36864L     // 192*192
#define M1  18432L     // 2*96*96
#define M2  73728L     // 2*192*192

typedef __attribute__((ext_vector_type(8))) short short8;
typedef __attribute__((ext_vector_type(4))) float f32x4;
typedef unsigned short u16;

#define AS1 __attribute__((address_space(1)))
#define AS3 __attribute__((address_space(3)))

__device__ __forceinline__ short f2bf(float f)
{
    unsigned u = __builtin_bit_cast(unsigned, f);
    u = (u + 0x7fff + ((u >> 16) & 1)) >> 16;   // RNE
    return (short)u;
}
__device__ __forceinline__ float bf2f(u16 u)
{
    unsigned x = ((unsigned)u) << 16;
    return __builtin_bit_cast(float, x);
}
__device__ __forceinline__ float gelu_exact(float v)
{
    return 0.5f * v * (1.0f + erff(v * 0.70710678118654752f));
}

// ---------------------------------------------------------------------------
// wcvt: one-time weight conversions.
// Transposed [N][K] jobs (16-k x 256-n tiles): proj 0..31, k 32..63, v 64..95,
// fc1 96..127 (16 kt x 2 n-halves), fc2 128..159.
// qwN (straight [ci][co] bf16 copy of q_w): 160..175.  kvb concat: 176.
// grid(177).
// ---------------------------------------------------------------------------
__global__ __launch_bounds__(256) void wcvt(
    const float* __restrict__ pw, const float* __restrict__ kw,
    const float* __restrict__ vw, const float* __restrict__ qw,
    const float* __restrict__ f1, const float* __restrict__ f2,
    const float* __restrict__ kb, const float* __restrict__ vb,
    u16* __restrict__ pwT, u16* __restrict__ kwT, u16* __restrict__ vwT,
    u16* __restrict__ f1T, u16* __restrict__ f2T,
    u16* __restrict__ qwN, float* __restrict__ kvb)
{
    int bx = blockIdx.x, t = threadIdx.x;
    if (bx >= 176) {                      // kvb concat
        kvb[t] = kb[t];
        kvb[256 + t] = vb[t];
        return;
    }
    if (bx >= 160) {                      // qwN straight bf16 copy
        int k0 = (bx - 160) * 16;
#pragma unroll
        for (int kk = 0; kk < 16; ++kk)
            qwN[(long)(k0 + kk) * 256 + t] = (u16)f2bf(qw[(long)(k0 + kk) * 256 + t]);
        return;
    }
    const float* src; u16* dst; int K, ldN = 256, kt, n0 = 0;
    if (bx < 32)       { src = pw; dst = pwT; K = 512; kt = bx; }
    else if (bx < 64)  { src = kw; dst = kwT; K = 512; kt = bx - 32; }
    else if (bx < 96)  { src = vw; dst = vwT; K = 512; kt = bx - 64; }
    else if (bx < 128) { int j = bx - 96; src = f1; dst = f1T; K = 256;
                         ldN = 512; kt = j >> 1; n0 = (j & 1) * 256; }
    else               { src = f2; dst = f2T; K = 512; kt = bx - 128; }
    int n = n0 + t, k0 = kt * 16;
    short s[16];
#pragma unroll
    for (int kk = 0; kk < 16; ++kk) s[kk] = f2bf(src[(long)(k0 + kk) * ldN + n]);
    *(short8*)&dst[(long)n * K + k0]     = *(short8*)&s[0];
    *(short8*)&dst[(long)n * K + k0 + 8] = *(short8*)&s[8];
}

// ---------------------------------------------------------------------------
__device__ __forceinline__ float pe4(int t, float e)
{
    if (t == 0) return sinf(e);
    if (t == 1) return cosf(e);
    if (t == 2) return sinf(e * 0.01f);
    return cosf(e * 0.01f);
}

// ---------------------------------------------------------------------------
// x1t: coalesced NCHW fp32 -> row-major bf16 transpose of x1 ([m][512]),
// with the pooled-k window sums AND the kg sine-pos folded in.
// grid 1536 = b*768 + cg*96 + y  (cg: 8 groups of 64 ch).
// ---------------------------------------------------------------------------
__global__ __launch_bounds__(256) void x1t(
    const float* __restrict__ x1, u16* __restrict__ x1bf, float* __restrict__ kg)
{
    __shared__ short T[6144];         // 96 pix x 32 words (64 ch bf16), swizzled
    __shared__ float rw[64][8];       // per-(ch, window-x) row partial sums
    const int blk = blockIdx.x;
    const int b = blk / 768, rem = blk % 768;
    const int cg = rem / 96, y = rem % 96;
    const int t = threadIdx.x;

    ((float2*)rw)[t] = float2{0.f, 0.f};
    __syncthreads();

    const float* src = x1 + ((long)(b * 512 + cg * 64)) * HW1 + (long)y * 96;
#pragma unroll
    for (int k = 0; k < 6; ++k) {
        int idx = t + k * 256;                 // < 1536
        int c = idx / 24, col4 = idx % 24;
        float4 v = *(const float4*)(src + (long)c * HW1 + col4 * 4);
        atomicAdd(&rw[c][col4 / 3], v.x + v.y + v.z + v.w);
        int chh = c >> 1, cb = c & 1;
        const float* vf = (const float*)&v;
#pragma unroll
        for (int j = 0; j < 4; ++j) {
            int pix = col4 * 4 + j;
            int word = pix * 32 + (chh ^ (((pix >> 2) & 7) << 2));
            T[word * 2 + cb] = f2bf(vf[j]);
        }
    }
    __syncthreads();
    u16* dst = x1bf + ((long)b * HW1 + (long)y * 96) * 512 + cg * 64;
#pragma unroll
    for (int k = 0; k < 3; ++k) {
        int idx = t + k * 256;                 // < 768
        int pix = idx >> 3, j = idx & 7;
        int w0 = pix * 32 + ((j * 4) ^ (((pix >> 2) & 7) << 2));
        *(short8*)(dst + (long)pix * 512 + j * 8) = *(short8*)&T[w0 * 2];
    }

    // pooled-k finalize: 512 cells (64 ch x 8 wx), 2 per thread
    {
        int wy = y / 12;
#pragma unroll
        for (int u = 0; u < 2; ++u) {
            int cell = t * 2 + u;
            int c = cell >> 3, wx = cell & 7;
            atomicAdd(kg + (long)(b * 64 + wy * 8 + wx) * 512 + cg * 64 + c,
                      rw[c][wx] * (1.0f / 144.0f));
        }
    }
    // kg sine-pos: added exactly once per (win, ch) by the y%12==0 blocks
    if (y % 12 == 0) {
        const float TWO_PI = 6.283185307179586f;
        int wy = y / 12;
#pragma unroll
        for (int u = 0; u < 2; ++u) {
            int cell = t * 2 + u;
            int gxx = cell & 7, c = cg * 64 + (cell >> 3);
            float pos;
            if (wy < 4) pos = pe4(wy,     (gxx + 1) * (TWO_PI / (8.0f + 1e-5f)));
            else        pos = pe4(wy - 4, (c + 1)   * (TWO_PI / (512.0f + 1e-5f)));
            atomicAdd(kg + (long)(b * 64 + wy * 8 + gxx) * 512 + c, pos);
        }
    }
}

// ---------------------------------------------------------------------------
// x2t: coalesced NCHW fp32 -> NHWC(pixel-major) bf16 transpose of x2, with the
// pooled-q window sums AND the qg sine-pos folded in. grid 1536.
// ---------------------------------------------------------------------------
__global__ __launch_bounds__(256) void x2t(
    const float* __restrict__ x2, u16* __restrict__ x2pm, float* __restrict__ qg)
{
    __shared__ short T[12288];        // 192 pix x 32 words (64 ch bf16), swizzled
    __shared__ float qsum[64][8];
    const int blk = blockIdx.x;
    const int b = blk / 768, rem = blk % 768;
    const int cg = rem / 192, h = rem % 192;
    const int t = threadIdx.x;

    ((float2*)qsum)[t] = float2{0.f, 0.f};
    __syncthreads();

    const float* src = x2 + ((long)(b * 256 + cg * 64) * 192 + h) * 192;
#pragma unroll
    for (int k = 0; k < 12; ++k) {
        int idx = t + k * 256;                 // < 3072
        int c = idx / 48, col4 = idx % 48;
        float4 v = *(const float4*)(src + (long)c * HW2 + col4 * 4);
        atomicAdd(&qsum[c][col4 / 6], v.x + v.y + v.z + v.w);
        int chh = c >> 1, cb = c & 1;
        const float* vf = (const float*)&v;
#pragma unroll
        for (int j = 0; j < 4; ++j) {
            int pix = col4 * 4 + j;
            int word = pix * 32 + (chh ^ (((pix >> 2) & 7) << 2));
            T[word * 2 + cb] = f2bf(vf[j]);
        }
    }
    __syncthreads();

    u16* dst = x2pm + ((long)b * HW2 + (long)h * 192) * 256 + cg * 64;
#pragma unroll
    for (int k = 0; k < 6; ++k) {
        int idx = t + k * 256;                 // < 1536
        int pix = idx >> 3, j = idx & 7;
        int w0 = pix * 32 + ((j * 4) ^ (((pix >> 2) & 7) << 2));
        *(short8*)(dst + (long)pix * 256 + j * 8) = *(short8*)&T[w0 * 2];
    }

    // pooled-q finalize: 512 cells, 2 per thread
    {
        int wy = h / 24;
#pragma unroll
        for (int u = 0; u < 2; ++u) {
            int cell = t * 2 + u;
            int c = cell >> 3, wx = cell & 7;
            atomicAdd(qg + (long)(b * 64 + wy * 8 + wx) * 256 + cg * 64 + c,
                      qsum[c][wx] * (1.0f / 576.0f));
        }
    }
    // qg sine-pos: added exactly once per (win, ch) by the h%24==0 blocks
    if (h % 24 == 0) {
        const float TWO_PI = 6.283185307179586f;
        int wy = h / 24;
#pragma unroll
        for (int u = 0; u < 2; ++u) {
            int cell = t * 2 + u;
            int gxx = cell & 7, c = cg * 64 + (cell >> 3);
            float pos;
            if (wy < 4) pos = pe4(wy,     (gxx + 1) * (TWO_PI / (8.0f + 1e-5f)));
            else        pos = pe4(wy - 4, (c + 1)   * (TWO_PI / (256.0f + 1e-5f)));
            atomicAdd(qg + (long)(b * 64 + wy * 8 + gxx) * 256 + c, pos);
        }
    }
}

// ---------------------------------------------------------------------------
// proj_ln: scb = LN(x1bf @ pwT^T + proj_b) -> bf16. BM=64, BN=256 (full row),
// K=512. LN in-register in the epilogue (16-lane-group shfl_xor reduce).
// grid(288).
// ---------------------------------------------------------------------------
__global__ __launch_bounds__(256) void proj_ln(
    const u16* __restrict__ A, const u16* __restrict__ BT,
    const float* __restrict__ bias, const float* __restrict__ g,
    const float* __restrict__ beta, u16* __restrict__ Cout)
{
    __shared__ short pool[64 * 72 + 256 * 72];   // As | Bs ; ob[64][264] aliases
    short* As = pool;
    short* Bs = pool + 64 * 72;
    const int t = threadIdx.x;
    const long m0 = (long)blockIdx.x * 64;
    const int w = t >> 6, lane = t & 63;
    const int lm = lane & 15, lq = lane >> 4;

    f32x4 acc[16] = {};
    for (int k0 = 0; k0 < 512; k0 += 64) {
#pragma unroll
        for (int it = 0; it < 2; ++it) {
            int idx = t + it * 256;
            int r = idx >> 3, q = idx & 7;
            *(short8*)&As[r * 72 + q * 8] = *(const short8*)(A + (m0 + r) * 512 + k0 + q * 8);
        }
#pragma unroll
        for (int it = 0; it < 8; ++it) {
            int idx = t + it * 256;
            int n = idx >> 3, q = idx & 7;
            *(short8*)&Bs[n * 72 + q * 8] = *(const short8*)(BT + (long)n * 512 + k0 + q * 8);
        }
        __syncthreads();
#pragma unroll
        for (int kk = 0; kk < 64; kk += 32) {
            short8 af = *(short8*)&As[(w * 16 + lm) * 72 + kk + lq * 8];
#pragma unroll
            for (int c = 0; c < 16; ++c) {
                short8 bf = *(short8*)&Bs[(c * 16 + lm) * 72 + kk + lq * 8];
                acc[c] = __builtin_amdgcn_mfma_f32_16x16x32_bf16(af, bf, acc[c], 0, 0, 0);
            }
        }
        __syncthreads();
    }
#pragma unroll
    for (int c = 0; c < 16; ++c) {
        float bv = bias[c * 16 + lm];
#pragma unroll
        for (int i = 0; i < 4; ++i) acc[c][i] += bv;
    }
    short* ob = pool;       // [64][264]
#pragma unroll
    for (int i = 0; i < 4; ++i) {
        float s = 0.f, s2 = 0.f;
#pragma unroll
        for (int c = 0; c < 16; ++c) { float v = acc[c][i]; s += v; s2 += v * v; }
#pragma unroll
        for (int o = 8; o > 0; o >>= 1) {
            s  += __shfl_xor(s,  o, 64);
            s2 += __shfl_xor(s2, o, 64);
        }
        float mean = s * (1.0f / 256.0f);
        float var  = s2 * (1.0f / 256.0f) - mean * mean;
        float rs   = rsqrtf(var + 1e-5f);
        int row = w * 16 + lq * 4 + i;
#pragma unroll
        for (int c = 0; c < 16; ++c) {
            int col = c * 16 + lm;
            ob[row * 264 + col] = f2bf((acc[c][i] - mean) * rs * g[col] + beta[col]);
        }
    }
    __syncthreads();
    {
        int sr = t >> 2, q4 = (t & 3) * 64;
        u16* Cp = Cout + (m0 + sr) * 256 + q4;
#pragma unroll
        for (int q = 0; q < 8; ++q)
            *(short8*)(Cp + q * 8) = *(short8*)&ob[sr * 264 + q4 + q * 8];
    }
}

// ---------------------------------------------------------------------------
// gemm_lds: C = A(bf16 [M][ldA]) @ BT^T + bias.  BT bf16 [N][K] (n-major).
// BM=BN=128, BK=64, mfma 16x16x32. Staging via global_load_lds (dwordx4):
// LDS tiles are LINEAR [128][64] (gload_lds needs contiguous dest); the T2
// XOR swizzle (col ^ ((row&7)<<3) shorts) is applied on the SOURCE address
// and again on the ds_read side (Guideline 21), giving 2-way (free) bank
// aliasing. 1D grid with chunked-XCD decode: same-row-panel blocks are
// consecutive on one XCD -> A-panel fetched once per XCD. EPI 1 = gelu.
// ---------------------------------------------------------------------------
template<int EPI>
__global__ __launch_bounds__(256) void gemm_lds(
    const u16* __restrict__ A, const u16* __restrict__ BT,
    const float* __restrict__ bias, u16* __restrict__ C,
    int N, int K, int ldA, int ny)
{
    __shared__ short pool[17408];  // As[128*64] Bs[128*64] | ob[128][136]
    short* As = pool;
    short* Bs = pool + 8192;
    const int tid = threadIdx.x;
    const int blk = blockIdx.x, G = gridDim.x, per = G >> 3;
    const int Lid = (blk & 7) * per + (blk >> 3);
    const int nx = G / ny;
    const int m0 = (Lid / nx) * 128;
    const int n0 = (Lid % nx) * 128;
    const int w = tid >> 6, lane = tid & 63;
    const int wm = (w & 1) * 64, wn = (w >> 1) * 64;
    const int lm = lane & 15, lq = lane >> 4;

    // staging geometry: wave w stages rows [w*32, w*32+32), 4 instrs x 8 rows.
    // lane -> row w*32 + i*8 + (lane>>3), chunk (lane&7)*8 shorts; source col
    // pre-swizzled so linear LDS holds the swizzled layout.
    const int srow = w * 32 + (lane >> 3);
    const int scs  = ((lane & 7) * 8) ^ ((lane >> 3) << 3);   // shorts
    const u16* Ap = A  + (long)(m0 + srow) * ldA + scs;
    const u16* Bp = BT + (long)(n0 + srow) * K   + scs;
    const int rsw = (lm & 7) << 3;                            // read-side XOR

    f32x4 acc[4][4] = {};

    for (int k0 = 0; k0 < K; k0 += 64) {
#pragma unroll
        for (int i = 0; i < 4; ++i)
            __builtin_amdgcn_global_load_lds(
                (AS1 const void*)(Ap + (long)i * 8 * ldA + k0),
                (AS3 void*)&As[(w * 32 + i * 8) * 64], 16, 0, 0);
#pragma unroll
        for (int i = 0; i < 4; ++i)
            __builtin_amdgcn_global_load_lds(
                (AS1 const void*)(Bp + (long)i * 8 * K + k0),
                (AS3 void*)&Bs[(w * 32 + i * 8) * 64], 16, 0, 0);
        __syncthreads();
#pragma unroll
        for (int kk = 0; kk < 64; kk += 32) {
            short8 af[4], bfr[4];
#pragma unroll
            for (int r = 0; r < 4; ++r)
                af[r]  = *(short8*)&As[(wm + r * 16 + lm) * 64 + ((kk + lq * 8) ^ rsw)];
#pragma unroll
            for (int c = 0; c < 4; ++c)
                bfr[c] = *(short8*)&Bs[(wn + c * 16 + lm) * 64 + ((kk + lq * 8) ^ rsw)];
#pragma unroll
            for (int r = 0; r < 4; ++r)
#pragma unroll
                for (int c = 0; c < 4; ++c)
                    acc[r][c] = __builtin_amdgcn_mfma_f32_16x16x32_bf16(af[r], bfr[c], acc[r][c], 0, 0, 0);
        }
        __syncthreads();
    }

    short* ob = pool;   // [128][136]
#pragma unroll
    for (int r = 0; r < 4; ++r)
#pragma unroll
        for (int i = 0; i < 4; ++i) {
            int row = wm + r * 16 + lq * 4 + i;
#pragma unroll
            for (int c = 0; c < 4; ++c) {
                int jl = wn + c * 16 + lm;
                float v = acc[r][c][i] + bias[n0 + jl];
                if (EPI == 1) v = gelu_exact(v);
                ob[row * 136 + jl] = f2bf(v);
            }
        }
    __syncthreads();
    int m = tid >> 1, half = (tid & 1) * 64;
    u16* Cp = C + (long)(m0 + m) * N + n0 + half;
#pragma unroll
    for (int q = 0; q < 8; ++q)
        *(short8*)(Cp + q * 8) = *(short8*)&ob[m * 136 + half + q * 8];
}

// ---------------------------------------------------------------------------
// ktv_w: per (window, head): KtV = K^T V (MFMA), then the folded attention
// matrix W'T[co=h*32+j][ci] = sum_t KtV[t][j] * q_w[ci][h*32+t]  (bf16) and
// bias' = bq_h @ KtV. 1-wave blocks (no barriers needed). grid(1024).
// ---------------------------------------------------------------------------
__global__ __launch_bounds__(64) void ktv_w(
    const u16* __restrict__ kv16, const u16* __restrict__ qwN,
    const float* __restrict__ qb, u16* __restrict__ wT, float* __restrict__ bias_w)
{
    __shared__ short pool[10368 + 1280]; // kt[32*162] vt[32*162] | wout[32*264]
    short* kt  = pool;
    short* vt  = pool + 5184;
    short* kt2 = pool + 10368;           // [32][40]: kt2[j][t] = KtV[t][j]
    short* wout = pool;                  // aliases kt+vt (dead after KtV)

    const int blk = blockIdx.x;     // win*8 + head
    const int win = blk >> 3, hd = blk & 7;
    const int b = win >> 6, wy = (win >> 3) & 7, wx = win & 7;
    const int t = threadIdx.x;
    const int lm = t & 15, lq = t >> 4;

    // zero the p = 144..159 pad
    {
        int c = t >> 1, p0 = 144 + (t & 1) * 8;
#pragma unroll
        for (int j = 0; j < 8; ++j) {
            kt[c * 162 + p0 + j] = 0;
            vt[c * 162 + p0 + j] = 0;
        }
    }
    // stage transposed K/V tiles from combined kv16 [m][512]
    const int pq = t >> 2, c8 = (t & 3) * 8;
#pragma unroll
    for (int it = 0; it < 9; ++it) {
        int p = it * 16 + pq;
        int py = p / 12, px = p % 12;
        long m = (long)b * HW1 + (long)(wy * 12 + py) * 96 + wx * 12 + px;
        short8 kvk = *(const short8*)(kv16 + m * 512 + hd * 32 + c8);
        short8 kvv = *(const short8*)(kv16 + m * 512 + 256 + hd * 32 + c8);
#pragma unroll
        for (int j = 0; j < 8; ++j) {
            kt[(c8 + j) * 162 + p] = kvk[j];
            vt[(c8 + j) * 162 + p] = kvv[j];
        }
    }
    __syncthreads();
    // KtV[i][j] = sum_p K[p][i] V[p][j]
    f32x4 acc[2][2] = {};
#pragma unroll
    for (int kk = 0; kk < 160; kk += 32) {
        short8 af[2], bf[2];
#pragma unroll
        for (int r = 0; r < 2; ++r) af[r] = *(short8*)&kt[(r * 16 + lm) * 162 + kk + lq * 8];
#pragma unroll
        for (int c = 0; c < 2; ++c) bf[c] = *(short8*)&vt[(c * 16 + lm) * 162 + kk + lq * 8];
#pragma unroll
        for (int r = 0; r < 2; ++r)
#pragma unroll
            for (int c = 0; c < 2; ++c)
                acc[r][c] = __builtin_amdgcn_mfma_f32_16x16x32_bf16(af[r], bf[c], acc[r][c], 0, 0, 0);
    }
    // kt2[j][t] = KtV[t][j]  (C layout: m=t=r*16+lq*4+i, n=j=c*16+lm)
#pragma unroll
    for (int r = 0; r < 2; ++r)
#pragma unroll
        for (int c = 0; c < 2; ++c)
#pragma unroll
            for (int i = 0; i < 4; ++i)
                kt2[(c * 16 + lm) * 40 + r * 16 + lq * 4 + i] = f2bf(acc[r][c][i]);
    __syncthreads();
    // bias' = bq_h @ KtV  (fp32)
    if (t < 32) {
        float s = 0.f;
#pragma unroll
        for (int tt = 0; tt < 32; ++tt)
            s += bf2f((u16)kt2[t * 40 + tt]) * qb[hd * 32 + tt];
        bias_w[(long)blk * 32 + t] = s;
    }
    // W'T[j][ci] = sum_t kt2[j][t] * qwN[ci][hd*32+t]
    short8 af2[2];
#pragma unroll
    for (int r = 0; r < 2; ++r) af2[r] = *(short8*)&kt2[(r * 16 + lm) * 40 + lq * 8];
#pragma unroll
    for (int nt = 0; nt < 16; ++nt) {
        short8 bf = *(const short8*)(qwN + (long)(nt * 16 + lm) * 256 + hd * 32 + lq * 8);
        f32x4 a2[2] = {};
#pragma unroll
        for (int r = 0; r < 2; ++r)
            a2[r] = __builtin_amdgcn_mfma_f32_16x16x32_bf16(af2[r], bf, a2[r], 0, 0, 0);
#pragma unroll
        for (int r = 0; r < 2; ++r)
#pragma unroll
            for (int i = 0; i < 4; ++i)
                wout[(r * 16 + lq * 4 + i) * 264 + nt * 16 + lm] = f2bf(a2[r][i]);
    }
    __syncthreads();
    {
        int row = t >> 1, half = (t & 1) * 128;
        u16* dst = wT + ((long)blk * 32 + row) * 256 + half;
#pragma unroll
        for (int q = 0; q < 16; ++q)
            *(short8*)(dst + q * 8) = *(short8*)&wout[row * 264 + half + q * 8];
    }
}

// ---------------------------------------------------------------------------
// wattn_ln3: fused  hln = LN( x2 + x2@W'_win + b'_win + up(og) ) -> bf16.
// W' = Wq @ blockdiag(KtV) precomputed by ktv_w. Block = one 2-row window
// strip (48 px) x 256 ch. grid(1536). Chunked-XCD decode: all 12 strips of a
// window run consecutively on ONE XCD -> its 131 KB W' is L2-local (16 win x
// 131 KB = 2.1 MB per XCD L2).
// ---------------------------------------------------------------------------
__global__ __launch_bounds__(256) void wattn_ln3(
    const u16* __restrict__ x2pm, const u16* __restrict__ wT,
    const float* __restrict__ bias_w, const float* __restrict__ og,
    u16* __restrict__ hln, const float* __restrict__ n1g,
    const float* __restrict__ n1b)
{
    __shared__ short qs[48 * 288];           // 27648 B

    const int t = threadIdx.x;
    const int blk = blockIdx.x;
    const int Lid = (blk & 7) * 192 + (blk >> 3);   // chunked XCD transform
    const int strip = Lid % 12, win = Lid / 12;
    const int b = win >> 6, wy = (win >> 3) & 7, wxw = win & 7;
    const int hh0 = wy * 24 + strip * 2;
    const int w = t >> 6, lane = t & 63;
    const int lm = lane & 15, lq = lane >> 4;

    long pbase[3];
#pragma unroll
    for (int r = 0; r < 3; ++r) {
        int p = r * 16 + lm;
        pbase[r] = ((long)b * HW2 + (long)(hh0 + p / 24) * 192 + wxw * 24 + (p % 24)) * 256;
    }
    const u16* wbase = wT + (long)win * 256 * 256;   // rows indexed by co

    // ---- phase 1: o = x2 @ W'^T (+ b') ----
    f32x4 acc[3][4] = {};
#pragma unroll 2
    for (int kc = 0; kc < 8; ++kc) {
        const int ko = kc * 32 + lq * 8;
        short8 af[3], bfr[4];
#pragma unroll
        for (int r = 0; r < 3; ++r)
            af[r] = *(const short8*)(x2pm + pbase[r] + ko);
#pragma unroll
        for (int c = 0; c < 4; ++c)
            bfr[c] = *(const short8*)(wbase + (long)(w * 64 + c * 16 + lm) * 256 + ko);
#pragma unroll
        for (int r = 0; r < 3; ++r)
#pragma unroll
            for (int c = 0; c < 4; ++c)
                acc[r][c] = __builtin_amdgcn_mfma_f32_16x16x32_bf16(af[r], bfr[c], acc[r][c], 0, 0, 0);
    }

    // ---- o (+b') -> qs bf16 (XOR-swizzled <<4: conflict-free writes) ----
#pragma unroll
    for (int c = 0; c < 4; ++c) {
        float bv = bias_w[(long)win * 256 + w * 64 + c * 16 + lm];
#pragma unroll
        for (int r = 0; r < 3; ++r)
#pragma unroll
            for (int i = 0; i < 4; ++i) {
                int p = r * 16 + lq * 4 + i;
                int col = w * 64 + c * 16 + lm;
                qs[p * 288 + (col ^ (((p >> 2) & 3) << 4))] = f2bf(acc[r][c][i] + bv);
            }
    }
    __syncthreads();

    // ---- phase 3: x = resid + o + up(og); LN over 256 ch; wave w: 12 px ----
    float4 g4 = *(const float4*)(n1g + lane * 4);
    float4 b4 = *(const float4*)(n1b + lane * 4);
    const float* ogb0 = og + (long)b * 64 * 256;
#pragma unroll
    for (int pp = 0; pp < 12; ++pp) {
        int p = w * 12 + pp;
        int hh = hh0 + (p / 24), ww = wxw * 24 + (p % 24);
        float fy = hh * (7.0f / 191.0f);
        int y0 = (int)fy; int y1 = min(y0 + 1, 7); float wyf = fy - y0;
        float fx = ww * (7.0f / 191.0f);
        int x0 = (int)fx; int x1 = min(x0 + 1, 7); float wxf = fx - x0;
        float w00 = (1.f - wyf) * (1.f - wxf), w01 = (1.f - wyf) * wxf;
        float w10 = wyf * (1.f - wxf),         w11 = wyf * wxf;
        float4 q00 = *(const float4*)(ogb0 + (y0 * 8 + x0) * 256 + lane * 4);
        float4 q01 = *(const float4*)(ogb0 + (y0 * 8 + x1) * 256 + lane * 4);
        float4 q10 = *(const float4*)(ogb0 + (y1 * 8 + x0) * 256 + lane * 4);
        float4 q11 = *(const float4*)(ogb0 + (y1 * 8 + x1) * 256 + lane * 4);
        long pix = (long)b * HW2 + (long)hh * 192 + ww;
        ushort4 rv = *(const ushort4*)(x2pm + pix * 256 + lane * 4);
        int sw = ((p >> 2) & 3) << 4;
        ushort4 ov = *(ushort4*)&qs[p * 288 + ((lane * 4) ^ sw)];
        float xv0 = bf2f(rv.x) + bf2f(ov.x) + (w00 * q00.x + w01 * q01.x + w10 * q10.x + w11 * q11.x);
        float xv1 = bf2f(rv.y) + bf2f(ov.y) + (w00 * q00.y + w01 * q01.y + w10 * q10.y + w11 * q11.y);
        float xv2 = bf2f(rv.z) + bf2f(ov.z) + (w00 * q00.z + w01 * q01.z + w10 * q10.z + w11 * q11.z);
        float xv3 = bf2f(rv.w) + bf2f(ov.w) + (w00 * q00.w + w01 * q01.w + w10 * q10.w + w11 * q11.w);
        float s  = xv0 + xv1 + xv2 + xv3;
        float s2 = xv0 * xv0 + xv1 * xv1 + xv2 * xv2 + xv3 * xv3;
#pragma unroll
        for (int o = 32; o > 0; o >>= 1) {
            s  += __shfl_xor(s,  o, 64);
            s2 += __shfl_xor(s2, o, 64);
        }
        float mean = s * (1.0f / 256.0f);
        float var  = s2 * (1.0f / 256.0f) - mean * mean;
        float rs   = rsqrtf(var + 1e-5f);
        ushort4 o4;
        o4.x = (u16)f2bf((xv0 - mean) * rs * g4.x + b4.x);
        o4.y = (u16)f2bf((xv1 - mean) * rs * g4.y + b4.y);
        o4.z = (u16)f2bf((xv2 - mean) * rs * g4.z + b4.z);
        o4.w = (u16)f2bf((xv3 - mean) * rs * g4.w + b4.w);
        *(ushort4*)(hln + pix * 256 + lane * 4) = o4;
    }
}

// ---------------------------------------------------------------------------
// gemm64m: the three global-branch 128x256 projections in ONE launch.
// grid(4,2,3): z=0 qg@q2_w->qg2, z=1 kg@k2_w->kg2, z=2 kg@v2_w->vgb.
// ---------------------------------------------------------------------------
__global__ __launch_bounds__(256) void gemm64m(
    const float* __restrict__ qg, const float* __restrict__ kg,
    const float* __restrict__ q2w, const float* __restrict__ q2b,
    const float* __restrict__ k2w, const float* __restrict__ k2b,
    const float* __restrict__ v2w, const float* __restrict__ v2b,
    float* __restrict__ qg2, float* __restrict__ kg2, float* __restrict__ vgb)
{
    const float* A; const float* Bm; const float* bias; float* C; int K, ldA;
    int z = blockIdx.z;
    if (z == 0)      { A = qg; Bm = q2w; bias = q2b; C = qg2; K = 256; ldA = 256; }
    else if (z == 1) { A = kg; Bm = k2w; bias = k2b; C = kg2; K = 512; ldA = 512; }
    else             { A = kg; Bm = v2w; bias = v2b; C = vgb; K = 512; ldA = 512; }
    const int N = 256;
    constexpr int BK = 16;
    __shared__ float As[BK][68];
    __shared__ float Bs[BK][68];
    const int tid = threadIdx.x;
    const int m0 = blockIdx.y * 64;
    const int n0 = blockIdx.x * 64;
    const int tm = (tid >> 4) << 2;
    const int tn = (tid & 15) << 2;
    float acc[4][4] = {};
    for (int k0 = 0; k0 < K; k0 += BK) {
#pragma unroll
        for (int it = 0; it < 4; ++it) {
            int idx = tid + it * 256;
            int my = idx >> 4, kx = idx & 15;
            As[kx][my] = A[(long)(m0 + my) * ldA + (k0 + kx)];
        }
#pragma unroll
        for (int it = 0; it < 4; ++it) {
            int idx = tid + it * 256;
            int ky = idx >> 6, nx = idx & 63;
            Bs[ky][nx] = Bm[(long)(k0 + ky) * N + (n0 + nx)];
        }
        __syncthreads();
#pragma unroll
        for (int kk = 0; kk < BK; ++kk) {
            float a[4], b[4];
#pragma unroll
            for (int i = 0; i < 4; ++i) a[i] = As[kk][tm + i];
#pragma unroll
            for (int j = 0; j < 4; ++j) b[j] = Bs[kk][tn + j];
#pragma unroll
            for (int i = 0; i < 4; ++i)
#pragma unroll
                for (int j = 0; j < 4; ++j) acc[i][j] += a[i] * b[j];
        }
        __syncthreads();
    }
#pragma unroll
    for (int i = 0; i < 4; ++i) {
        long row = (long)(m0 + tm + i) * N;
#pragma unroll
        for (int j = 0; j < 4; ++j)
            C[row + n0 + tn + j] = acc[i][j] + bias[n0 + tn + j];
    }
}

// ---------------------------------------------------------------------------
__global__ __launch_bounds__(256) void gattn(
    const float* __restrict__ qg2, const float* __restrict__ kg2,
    const float* __restrict__ vg, float* __restrict__ og)
{
    __shared__ float qh[64][33], kh[64][33], vh[64][33];
    __shared__ float S[64][65];
    __shared__ float rinv[64];
    int blk = blockIdx.x;
    int b = blk >> 3, hd = blk & 7;
    int t = threadIdx.x;
#pragma unroll
    for (int it = 0; it < 8; ++it) {
        int idx = t + it * 256;
        int n = idx >> 5, i = idx & 31;
        long src = (long)(b * 64 + n) * 256 + hd * 32 + i;
        qh[n][i] = qg2[src];
        kh[n][i] = kg2[src];
        vh[n][i] = vg[src];
    }
    __syncthreads();
    int r = t >> 2, qq = t & 3, c0 = qq * 16;
    for (int c = c0; c < c0 + 16; ++c) {
        float s = 0.f;
#pragma unroll
        for (int i = 0; i < 32; ++i) s += qh[r][i] * kh[c][i];
        S[r][c] = s;
    }
    __syncthreads();
    float mx = -1e30f;
    for (int c = c0; c < c0 + 16; ++c) mx = fmaxf(mx, S[r][c]);
    mx = fmaxf(mx, __shfl_xor(mx, 1, 64));
    mx = fmaxf(mx, __shfl_xor(mx, 2, 64));
    float sm = 0.f;
    for (int c = c0; c < c0 + 16; ++c) {
        float e = expf(S[r][c] - mx);
        S[r][c] = e;
        sm += e;
    }
    sm += __shfl_xor(sm, 1, 64);
    sm += __shfl_xor(sm, 2, 64);
    if (qq == 0) rinv[r] = 1.0f / sm;
    __syncthreads();
    int n = t >> 2, j0 = (t & 3) * 8;
    float inv = rinv[n];
    for (int j = j0; j < j0 + 8; ++j) {
        float s = 0.f;
        for (int c = 0; c < 64; ++c) s += S[n][c] * vh[c][j];
        og[(long)(b * 64 + n) * 256 + hd * 32 + j] = s * inv;
    }
}

// ---------------------------------------------------------------------------
// out = LN(mlp + bilinear_ac(sc, 96->192)) -> NCHW fp32. bf16 inputs.
// ---------------------------------------------------------------------------
__global__ __launch_bounds__(256) void final_k3(
    const u16* __restrict__ mlp, const u16* __restrict__ sc,
    const float* __restrict__ g, const float* __restrict__ bb,
    float* __restrict__ out)
{
    __shared__ float lnb[32][258];
    int blk = blockIdx.x;              // b*1152 + hh*6 + strip
    int b = blk / 1152;
    int rem = blk - b * 1152;
    int hh = rem / 6, ww0 = (rem % 6) * 32;
    int wv = threadIdx.x >> 6, lane = threadIdx.x & 63;
    int c0 = lane * 4;
    float4 g4 = *(const float4*)(g + c0);
    float4 b4 = *(const float4*)(bb + c0);
    float fy = hh * (95.0f / 191.0f);
    int y0 = (int)fy; int y1 = min(y0 + 1, 95); float wy = fy - y0;
    const u16* scb = sc + (long)b * 9216 * 256 + c0;
#pragma unroll
    for (int i = 0; i < 8; ++i) {
        int p = wv * 8 + i;
        int ww = ww0 + p;
        float fx = ww * (95.0f / 191.0f);
        int x0 = (int)fx; int x1 = min(x0 + 1, 95); float wx = fx - x0;
        ushort4 u00 = *(const ushort4*)(scb + (long)(y0 * 96 + x0) * 256);
        ushort4 u01 = *(const ushort4*)(scb + (long)(y0 * 96 + x1) * 256);
        ushort4 u10 = *(const ushort4*)(scb + (long)(y1 * 96 + x0) * 256);
        ushort4 u11 = *(const ushort4*)(scb + (long)(y1 * 96 + x1) * 256);
        long m = ((long)b * 192 + hh) * 192 + ww;
        ushort4 um = *(const ushort4*)(mlp + m * 256 + c0);
        float w00 = (1.f - wy) * (1.f - wx), w01 = (1.f - wy) * wx;
        float w10 = wy * (1.f - wx),         w11 = wy * wx;
        float xv0 = bf2f(um.x) + w00 * bf2f(u00.x) + w01 * bf2f(u01.x) + w10 * bf2f(u10.x) + w11 * bf2f(u11.x);
        float xv1 = bf2f(um.y) + w00 * bf2f(u00.y) + w01 * bf2f(u01.y) + w10 * bf2f(u10.y) + w11 * bf2f(u11.y);
        float xv2 = bf2f(um.z) + w00 * bf2f(u00.z) + w01 * bf2f(u01.z) + w10 * bf2f(u10.z) + w11 * bf2f(u11.z);
        float xv3 = bf2f(um.w) + w00 * bf2f(u00.w) + w01 * bf2f(u01.w) + w10 * bf2f(u10.w) + w11 * bf2f(u11.w);
        float s  = xv0 + xv1 + xv2 + xv3;
        float s2 = xv0 * xv0 + xv1 * xv1 + xv2 * xv2 + xv3 * xv3;
#pragma unroll
        for (int o = 32; o > 0; o >>= 1) {
            s  += __shfl_xor(s,  o, 64);
            s2 += __shfl_xor(s2, o, 64);
        }
        float mean = s * (1.0f / 256.0f);
        float var  = s2 * (1.0f / 256.0f) - mean * mean;
        float rs   = rsqrtf(var + 1e-5f);
        lnb[p][c0 + 0] = (xv0 - mean) * rs * g4.x + b4.x;
        lnb[p][c0 + 1] = (xv1 - mean) * rs * g4.y + b4.y;
        lnb[p][c0 + 2] = (xv2 - mean) * rs * g4.z + b4.z;
        lnb[p][c0 + 3] = (xv3 - mean) * rs * g4.w + b4.w;
    }
    __syncthreads();
    int tw = threadIdx.x & 31, cg = threadIdx.x >> 5;
#pragma unroll
    for (int cc = 0; cc < 32; ++cc) {
        int c = cg * 32 + cc;
        out[((long)(b * 256 + c) * 192 + hh) * 192 + ww0 + tw] = lnb[tw][c];
    }
}

// ---------------------------------------------------------------------------
extern "C" void kernel_launch(void* const* d_in, const int* in_sizes, int n_in,
                              void* d_out, int out_size, void* d_ws, size_t ws_size,
                              hipStream_t stream)
{
    const float* x1     = (const float*)d_in[0];
    const float* x2     = (const float*)d_in[1];
    const float* q_w    = (const float*)d_in[2];
    const float* q_b    = (const float*)d_in[3];
    const float* k_w    = (const float*)d_in[4];
    const float* k_b    = (const float*)d_in[5];
    const float* v_w    = (const float*)d_in[6];
    const float* v_b    = (const float*)d_in[7];
    const float* q2_w   = (const float*)d_in[8];
    const float* q2_b   = (const float*)d_in[9];
    const float* k2_w   = (const float*)d_in[10];
    const float* k2_b   = (const float*)d_in[11];
    const float* v2_w   = (const float*)d_in[12];
    const float* v2_b   = (const float*)d_in[13];
    const float* proj_w = (const float*)d_in[14];
    const float* proj_b = (const float*)d_in[15];
    const float* proj_g = (const float*)d_in[16];
    const float* proj_bt= (const float*)d_in[17];
    const float* n1_g   = (const float*)d_in[18];
    const float* n1_b   = (const float*)d_in[19];
    const float* n2_g   = (const float*)d_in[20];
    const float* n2_b   = (const float*)d_in[21];
    const float* fc1_w  = (const float*)d_in[22];
    const float* fc1_b  = (const float*)d_in[23];
    const float* fc2_w  = (const float*)d_in[24];
    const float* fc2_b  = (const float*)d_in[25];
    float* out = (float*)d_out;

    // workspace carve (bytes)
    char* p = (char*)d_ws;
    u16*   scb  = (u16*)p;    p += M1 * 256 * 2;        //  9.4 MB sc bf16
    u16*   pwT  = (u16*)p;    p += 262144;              //  weight slabs bf16 [N][K]
    u16*   kwT  = (u16*)p;    p += 262144;              //  (kwT+vwT contiguous = kv)
    u16*   vwT  = (u16*)p;    p += 262144;
    u16*   f1T  = (u16*)p;    p += 262144;
    u16*   f2T  = (u16*)p;    p += 262144;
    u16*   qwN  = (u16*)p;    p += 131072;              //  q_w bf16 [ci][co]
    float* kvb  = (float*)p;  p += 2048;                //  concat k_b|v_b
    float* bias_w = (float*)p; p += 131072;             //  b' per (win,co)
    u16*   wT   = (u16*)p;    p += 1024L * 32 * 256 * 2;//  16.8 MB W'T
    u16*   kv16 = (u16*)p;    p += M1 * 512 * 2;        //  18.9 MB k|v bf16
    u16*   hln  = (u16*)p;    p += M2 * 256 * 2;        //  37.7 MB
    u16*   h1c  = (u16*)p;    p += 36864L * 512 * 2;    //  37.7 MB (half-M hidden)
    u16*   mlpb = (u16*)p;    p += M2 * 256 * 2;        //  37.7 MB
    float* qg   = (float*)p;  p += 128L * 256 * 4;
    float* kg   = (float*)p;  p += 128L * 512 * 4;
    float* qg2  = (float*)p;  p += 128L * 256 * 4;
    float* kg2  = (float*)p;  p += 128L * 256 * 4;
    float* vgb  = (float*)p;  p += 128L * 256 * 4;
    float* ogb  = (float*)p;  p += 128L * 256 * 4;

    // aliases with disjoint lifetimes:
    u16* x2pm = mlpb;   // [x2t .. wattn_ln3] vs [MLP .. final_k3]
    u16* x1bf = hln;    // [x1t .. kv gemm]   vs [wattn_ln3 .. MLP]

    dim3 blk(256);

    // 0) zero pooled accumulators (qg & kg contiguous)
    hipMemsetAsync(qg, 0, (128L * 256 + 128L * 512) * 4, stream);

    // 1) one-time conversions; x1/x2 transposes with pooled sums + pos folded
    wcvt<<<dim3(177), blk, 0, stream>>>(proj_w, k_w, v_w, q_w, fc1_w, fc2_w,
                                        k_b, v_b, pwT, kwT, vwT, f1T, f2T,
                                        qwN, kvb);
    x1t<<<dim3(1536), blk, 0, stream>>>(x1, x1bf, kg);
    x2t<<<dim3(1536), blk, 0, stream>>>(x2, x2pm, qg);

    // 2) proj GEMM with fused LN -> bf16 sc
    proj_ln<<<dim3(288), blk, 0, stream>>>(x1bf, pwT, proj_b, proj_g, proj_bt, scb);

    // 3) k & v projections in ONE launch (N=512, kwT|vwT contiguous)
    gemm_lds<0><<<dim3(576), blk, 0, stream>>>(x1bf, kwT, kvb, kv16, 512, 512, 512, 144);

    // 4) per (window, head): KtV then folded W' and b'
    ktv_w<<<dim3(1024), dim3(64), 0, stream>>>(kv16, qwN, q_b, wT, bias_w);

    // 5-6) global projections (one launch) + global softmax attention
    gemm64m<<<dim3(4, 2, 3), blk, 0, stream>>>(qg, kg, q2_w, q2_b, k2_w, k2_b,
                                               v2_w, v2_b, qg2, kg2, vgb);
    gattn<<<dim3(16), blk, 0, stream>>>(qg2, kg2, vgb, ogb);

    // 7) fused folded-attn + residual + og upsample + LN1
    wattn_ln3<<<dim3(1536), blk, 0, stream>>>(x2pm, wT, bias_w, ogb, hln, n1_g, n1_b);

    // 8-9) MLP via LDS-staged GEMMs, 2 chunks x 2 launches (36864 rows each)
    for (int c2 = 0; c2 < 2; ++c2) {
        const u16* aoff = hln  + (long)c2 * 36864 * 256;
        u16*       coff = mlpb + (long)c2 * 36864 * 256;
        gemm_lds<1><<<dim3(1152), blk, 0, stream>>>(aoff, f1T, fc1_b, h1c, 512, 256, 256, 288);
        gemm_lds<0><<<dim3(576), blk, 0, stream>>>(h1c, f2T, fc2_b, coff, 256, 512, 512, 288);
    }

    // 10) out = LN(mlp + upsample(sc)) -> NCHW
    final_k3<<<dim3(2304), blk, 0, stream>>>(mlpb, scb, n2_g, n2_b, out);
}